// Round 19
// baseline (60.915 us; speedup 1.0000x reference)
//
#include <hip/hip_runtime.h>
#include <math.h>

#define BB 4
#define CC 256
#define HH 48
#define WI 48
#define NN (HH*WI)      // 2304
#define NHEAD 8
#define HD 32
#define PLANE ((size_t)NN*HD)
#define BUF   (BB*NHEAD*NN*HD)      // 2359296 elems per [9216,256] buffer

typedef unsigned short u16;
typedef __attribute__((ext_vector_type(8))) short bf16x8;
typedef __attribute__((ext_vector_type(4))) float f32x4;

__device__ inline u16 f2bf(float f) {          // RNE float->bf16
  union { float f; unsigned u; } v; v.f = f;
  unsigned r = v.u + 0x7FFFu + ((v.u >> 16) & 1u);
  return (u16)(r >> 16);
}
__device__ inline u16 f2bf_rna(float f) {      // cheap round (f>=0)
  union { float f; unsigned u; } v; v.f = f;
  return (u16)((v.u + 0x8000u) >> 16);
}

// ---------------------------------------------------------------------------
// Fused prep:
//   blocks [0,2304):    XT[b*N+n][c] = bf16(x[b][c][n])  (transpose tiles)
//   blocks [2304,2560): fp32->bf16 weight convert (W1 | W3)
//   blocks [2560,2576): W32[o][k] = sum_c w3[o][c]*w2[c][k]  (MFMA 64x64)
//   block  2576:        b23[o] = sum_c w3[o][c]*b2[c] + b3[o]
// ---------------------------------------------------------------------------
__global__ __launch_bounds__(256) void prep_kernel(
    const float* __restrict__ x, const float* __restrict__ w1,
    const float* __restrict__ w2, const float* __restrict__ w3,
    const float* __restrict__ b2, const float* __restrict__ b3,
    u16* __restrict__ XT, u16* __restrict__ W1b, u16* __restrict__ W3b,
    u16* __restrict__ W32b, float* __restrict__ b23) {
  __shared__ char smem[10240];
  const int bx = blockIdx.x;
  const int t = threadIdx.x;
  if (bx < 2304) {
    float (*T)[36] = (float(*)[36])smem;
    const int n0 = (bx % 72) * 32, c0 = ((bx / 72) & 7) * 32, b = bx / 576;
    const int c = t >> 3, n4 = (t & 7) * 4;
    *(float4*)&T[c][n4] = *(const float4*)&x[((size_t)b * CC + c0 + c) * NN + n0 + n4];
    __syncthreads();
    const int nn = t >> 3, c4 = (t & 7) * 4;
    ushort4 o;
    o.x = f2bf(T[c4 + 0][nn]); o.y = f2bf(T[c4 + 1][nn]);
    o.z = f2bf(T[c4 + 2][nn]); o.w = f2bf(T[c4 + 3][nn]);
    *(ushort4*)&XT[((size_t)b * NN + n0 + nn) * CC + c0 + c4] = o;
  } else if (bx < 2560) {
    const int i = ((bx - 2304) * 256 + t) * 4;
    const float* src; u16* dst; int off;
    if (i < 196608) { src = w1; dst = W1b; off = i; }
    else            { src = w3; dst = W3b; off = i - 196608; }
    float4 v = *(const float4*)&src[off];
    ushort4 o = {f2bf(v.x), f2bf(v.y), f2bf(v.z), f2bf(v.w)};
    *(ushort4*)&dst[off] = o;
  } else if (bx < 2576) {
    // W32 = w3 * w2  (A = w3 rows k-contig fp32->bf16; B[k][c] = w2[c][k] scalar)
    u16 (*As)[40] = (u16(*)[40])smem;
    u16 (*Ws)[40] = (u16(*)[40])&smem[5120];
    const int bb = bx - 2560;
    const int m0 = (bb & 3) * 64, n0 = (bb >> 2) * 64;
    const int lane = t & 63, ll = lane & 15, lh = lane >> 4;
    const int wv = t >> 6;
    const int wm = (wv >> 1) << 5, wj = (wv & 1) << 5;
    const bool isW = (t >= 128);
    const int r_ = (t & 127) >> 1;
    const int kh = (t & 1) << 4;
    f32x4 acc[2][2] = {};
    for (int k0 = 0; k0 < 256; k0 += 32) {
      __syncthreads();
      if (!isW) {
        const float* s = &w3[(size_t)(m0 + r_) * 256 + k0 + kh];
#pragma unroll
        for (int i = 0; i < 16; i += 4) {
          float4 v = *(const float4*)(s + i);
          As[r_][kh + i]     = f2bf(v.x);
          As[r_][kh + i + 1] = f2bf(v.y);
          As[r_][kh + i + 2] = f2bf(v.z);
          As[r_][kh + i + 3] = f2bf(v.w);
        }
      } else {
#pragma unroll
        for (int i = 0; i < 16; ++i)
          Ws[r_][kh + i] = f2bf(w2[(size_t)(k0 + kh + i) * 256 + n0 + r_]);
      }
      __syncthreads();
      bf16x8 af[2], bfv[2];
#pragma unroll
      for (int s = 0; s < 2; ++s) {
        af[s]  = *(const bf16x8*)&As[wm + s * 16 + ll][lh * 8];
        bfv[s] = *(const bf16x8*)&Ws[wj + s * 16 + ll][lh * 8];
      }
#pragma unroll
      for (int ms = 0; ms < 2; ++ms)
#pragma unroll
        for (int js = 0; js < 2; ++js)
          acc[ms][js] = __builtin_amdgcn_mfma_f32_16x16x32_bf16(af[ms], bfv[js], acc[ms][js], 0, 0, 0);
    }
#pragma unroll
    for (int js = 0; js < 2; ++js) {
      const int j = n0 + wj + js * 16 + ll;            // k-column of W32
#pragma unroll
      for (int ms = 0; ms < 2; ++ms) {
        const int row = m0 + wm + ms * 16 + (lh << 2); // o-row of W32
#pragma unroll
        for (int r = 0; r < 4; ++r)
          W32b[(size_t)(row + r) * 256 + j] = f2bf(acc[ms][js][r]);
      }
    }
  } else {
    // b23[o] = sum_c w3[o][c]*b2[c] + b3[o]
    float s = b3[t];
    const float* row = &w3[(size_t)t * 256];
    for (int c = 0; c < 256; c += 4) {
      float4 wv = *(const float4*)(row + c);
      float4 bv = *(const float4*)(b2 + c);
      s += wv.x * bv.x + wv.y * bv.y + wv.z * bv.z + wv.w * bv.w;
    }
    b23[t] = s;
  }
}

// ---------------------------------------------------------------------------
// MFMA GEMM core 128x128 (R4/R8-proven, used by qkv): K=256, 4 waves 2x2.
// Frag layout (HW-verified): A row=ll, B col=ll, k=lh*8+j; C/D row=lh*4+r, col=ll.
// ---------------------------------------------------------------------------
__device__ __forceinline__ void gemm_core(
    const u16* __restrict__ act, const u16* __restrict__ wb,
    int m0, int j0, u16 (&As)[128][40], u16 (&Ws)[128][40],
    f32x4 (&acc)[4][4], int tid) {
  const int lane = tid & 63, ll = lane & 15, lh = lane >> 4;
  const int wv = tid >> 6;
  const int wm = (wv >> 1) << 6, wj = (wv & 1) << 6;
  const int r_ = tid >> 1;
  const int kh = (tid & 1) << 4;
  for (int k0 = 0; k0 < CC; k0 += 32) {
    __syncthreads();
    bf16x8 a0 = *(const bf16x8*)&act[(size_t)(m0 + r_) * CC + k0 + kh];
    bf16x8 a1 = *(const bf16x8*)&act[(size_t)(m0 + r_) * CC + k0 + kh + 8];
    bf16x8 w0 = *(const bf16x8*)&wb[(size_t)(j0 + r_) * CC + k0 + kh];
    bf16x8 w1 = *(const bf16x8*)&wb[(size_t)(j0 + r_) * CC + k0 + kh + 8];
    *(bf16x8*)&As[r_][kh]     = a0;
    *(bf16x8*)&As[r_][kh + 8] = a1;
    *(bf16x8*)&Ws[r_][kh]     = w0;
    *(bf16x8*)&Ws[r_][kh + 8] = w1;
    __syncthreads();
    bf16x8 af[4], bfv[4];
#pragma unroll
    for (int s = 0; s < 4; ++s) {
      af[s]  = *(const bf16x8*)&As[wm + s * 16 + ll][lh * 8];
      bfv[s] = *(const bf16x8*)&Ws[wj + s * 16 + ll][lh * 8];
    }
#pragma unroll
    for (int ms = 0; ms < 4; ++ms)
#pragma unroll
      for (int js = 0; js < 4; ++js)
        acc[ms][js] = __builtin_amdgcn_mfma_f32_16x16x32_bf16(af[ms], bfv[js], acc[ms][js], 0, 0, 0);
  }
}

// ---------------------------------------------------------------------------
// MFMA GEMM core 64x64. 4 waves 2x2, wave = 32x32. ACCUMULATES into acc, so
// two back-to-back calls implement a K=512 concat GEMM (barrier at each
// k-step head makes LDS reuse across calls race-free).
// ---------------------------------------------------------------------------
__device__ __forceinline__ void gemm_core64(
    const u16* __restrict__ act, const u16* __restrict__ wb,
    int m0, int j0, u16 (&As)[64][40], u16 (&Ws)[64][40],
    f32x4 (&acc)[2][2], int tid) {
  const int lane = tid & 63, ll = lane & 15, lh = lane >> 4;
  const int wv = tid >> 6;
  const int wm = (wv >> 1) << 5, wj = (wv & 1) << 5;
  const bool isW = (tid >= 128);
  const int r_ = (tid & 127) >> 1;
  const int kh = (tid & 1) << 4;
  const u16* src = isW ? &wb[(size_t)(j0 + r_) * CC + kh]
                       : &act[(size_t)(m0 + r_) * CC + kh];
  u16* dst = isW ? &Ws[r_][kh] : &As[r_][kh];
  for (int k0 = 0; k0 < CC; k0 += 32) {
    __syncthreads();
    bf16x8 v0 = *(const bf16x8*)(src + k0);
    bf16x8 v1 = *(const bf16x8*)(src + k0 + 8);
    *(bf16x8*)dst       = v0;
    *(bf16x8*)(dst + 8) = v1;
    __syncthreads();
    bf16x8 af[2], bfv[2];
#pragma unroll
    for (int s = 0; s < 2; ++s) {
      af[s]  = *(const bf16x8*)&As[wm + s * 16 + ll][lh * 8];
      bfv[s] = *(const bf16x8*)&Ws[wj + s * 16 + ll][lh * 8];
    }
#pragma unroll
    for (int ms = 0; ms < 2; ++ms)
#pragma unroll
      for (int js = 0; js < 2; ++js)
        acc[ms][js] = __builtin_amdgcn_mfma_f32_16x16x32_bf16(af[ms], bfv[js], acc[ms][js], 0, 0, 0);
  }
}

// ---------------------------------------------------------------------------
// GEMM 1 (128x128): qkv = XT @ W1^T + b1 -> Q, K [B,H,N,32], VT [B,H,32,N]
// ---------------------------------------------------------------------------
__global__ __launch_bounds__(256) void qkv_gemm(
    const u16* __restrict__ XT, const u16* __restrict__ W1b,
    const float* __restrict__ bias,
    u16* __restrict__ Qb, u16* __restrict__ Kb, u16* __restrict__ VTb) {
  __shared__ u16 As[128][40];
  __shared__ u16 Ws[128][40];
  const int tid = threadIdx.x;
  const int m0 = blockIdx.x * 128, j0 = blockIdx.y * 128;
  f32x4 acc[4][4] = {};
  gemm_core(XT, W1b, m0, j0, As, Ws, acc, tid);

  const int lane = tid & 63, ll = lane & 15, lh = lane >> 4;
  const int wv = tid >> 6;
  const int wm = (wv >> 1) << 6, wj = (wv & 1) << 6;
  const int part = blockIdx.y >> 1;            // 0=Q 1=K 2=V (uniform)
  const int b = m0 / NN, n0 = m0 % NN;
#pragma unroll
  for (int js = 0; js < 4; ++js) {
    const int j = j0 + wj + js * 16 + ll;
    const float bj = bias[j];
    const int head = (j >> 5) & 7, d = j & 31;
#pragma unroll
    for (int ms = 0; ms < 4; ++ms) {
      const int nb = n0 + wm + ms * 16 + (lh << 2);
      if (part == 2) {
        ushort4 v = {f2bf(acc[ms][js][0] + bj), f2bf(acc[ms][js][1] + bj),
                     f2bf(acc[ms][js][2] + bj), f2bf(acc[ms][js][3] + bj)};
        *(ushort4*)&VTb[(((size_t)b * NHEAD + head) * HD + d) * NN + nb] = v;
      } else {
        u16* dst = (part == 0 ? Qb : Kb) + ((size_t)b * NHEAD + head) * PLANE;
#pragma unroll
        for (int r = 0; r < 4; ++r)
          dst[(size_t)(nb + r) * HD + d] = f2bf(acc[ms][js][r] + bj);
      }
    }
  }
}

// ---------------------------------------------------------------------------
// MFMA windowed attention (R18-proven BEST): 16x4 query tile, 2-row chunked
// double-buffered clamped staging, setprio, XCD swizzle. LDS 22.3 KB.
// ---------------------------------------------------------------------------
__global__ __launch_bounds__(256) void attn_mfma(
    const u16* __restrict__ Qb, const u16* __restrict__ Kb,
    const u16* __restrict__ VTb, u16* __restrict__ Ob) {
  __shared__ u16 Ks[2][64][32];   // [buf][slot = rr*32+key][dim]
  __shared__ u16 VTs[2][32][72];  // [buf][dim][slot] (pad 72)
  __shared__ u16 Ps[4][16][40];   // per-wave P [query][keyslot]
  const int bid0 = blockIdx.x;
  const int bid  = (bid0 & 7) * 144 + (bid0 >> 3);   // XCD swizzle (bijective)
  const int tile = bid % 36;      // 12 (th) x 3 (tw)
  const int head = (bid / 36) & 7;
  const int b    = bid / 288;
  const int th0 = (tile / 3) * 4, tw0 = (tile % 3) * 16;
  const int tid = threadIdx.x;
  const int wv = tid >> 6, lane = tid & 63;
  const int lh = lane >> 4, ll = lane & 15;
  const size_t plane = ((size_t)b * NHEAD + head) * PLANE;

  const int wlo = max(0, tw0 - 8);
  const int nw  = min(WI, tw0 + 24) - wlo;       // 24 or 32, block-uniform
  const int rlo = max(0, th0 - 8), rhi = min(HH, th0 + 12);   // even count

  const int qh = th0 + wv;                       // wave's query row
  const bf16x8 qfrag = *(const bf16x8*)&Qb[plane + (size_t)(qh * WI + tw0 + ll) * HD + lh * 8];

  int qw_r[4];
  float cb0[4], cb1[4];
  const int wk0 = wlo + ll;
  const int wk1 = wlo + 16 + ll;
#pragma unroll
  for (int r = 0; r < 4; ++r) {
    qw_r[r] = tw0 + (lh << 2) + r;
    cb0[r] = (abs(wk0 - qw_r[r]) <= 8) ? 0.0f : -30000.0f;
    cb1[r] = (wk1 < WI && abs(wk1 - qw_r[r]) <= 8) ? 0.0f : -30000.0f;
  }

  f32x4 o0 = {0.f, 0.f, 0.f, 0.f}, o1 = {0.f, 0.f, 0.f, 0.f};
  const f32x4 zf = {0.f, 0.f, 0.f, 0.f};
  float lsum[4] = {0.f, 0.f, 0.f, 0.f};
  const int sk_slot = tid >> 2, sk_d = (tid & 3) * 8;
  const int sk_rr = sk_slot >> 5;
  const int sk_c  = min(sk_slot & 31, nw - 1);
  const int sv_d = tid >> 3, sv_s = (tid & 7) * 8;
  const int sv_rr = sv_s >> 5;
  const int sv_c  = min(sv_s & 31, nw - 1);
  const float C2 = 0.25501651847296056f;         // (1/sqrt(32)) * log2(e)
  const int nch = (rhi - rlo) >> 1;

  {
    bf16x8 kv = *(const bf16x8*)&Kb[plane + (size_t)((rlo + sk_rr) * WI + wlo + sk_c) * HD + sk_d];
    bf16x8 vv = *(const bf16x8*)&VTb[plane + (size_t)sv_d * NN + (rlo + sv_rr) * WI + wlo + sv_c];
    *(bf16x8*)&Ks[0][sk_slot][sk_d] = kv;
    *(bf16x8*)&VTs[0][sv_d][sv_s] = vv;
  }

  int cur = 0;
  for (int c = 0; c < nch; ++c) {
    const int hk2 = rlo + (c << 1);
    bf16x8 nkv, nvv;
    const bool more = (c + 1 < nch);
    if (more) {
      nkv = *(const bf16x8*)&Kb[plane + (size_t)((hk2 + 2 + sk_rr) * WI + wlo + sk_c) * HD + sk_d];
      nvv = *(const bf16x8*)&VTb[plane + (size_t)sv_d * NN + (hk2 + 2 + sv_rr) * WI + wlo + sv_c];
    }
    __syncthreads();   // buf[cur] complete
#pragma unroll
    for (int rr = 0; rr < 2; ++rr) {
      const int hk = hk2 + rr;
      if (hk >= qh - 8 && hk <= qh + 8) {          // wave-uniform row window
        const int sb = rr << 5;
        __builtin_amdgcn_s_setprio(1);
        const bf16x8 k0 = *(const bf16x8*)&Ks[cur][sb + ll][lh * 8];
        const bf16x8 k1 = *(const bf16x8*)&Ks[cur][sb + 16 + ll][lh * 8];
        f32x4 s0 = __builtin_amdgcn_mfma_f32_16x16x32_bf16(qfrag, k0, zf, 0, 0, 0);
        f32x4 s1 = __builtin_amdgcn_mfma_f32_16x16x32_bf16(qfrag, k1, zf, 0, 0, 0);
#pragma unroll
        for (int r = 0; r < 4; ++r) {
          float e0 = exp2f(fmaf(s0[r], C2, cb0[r]));
          float e1 = exp2f(fmaf(s1[r], C2, cb1[r]));
          lsum[r] += e0 + e1;
          Ps[wv][(lh << 2) + r][ll]      = f2bf_rna(e0);
          Ps[wv][(lh << 2) + r][16 + ll] = f2bf_rna(e1);
        }
        const bf16x8 pa = *(const bf16x8*)&Ps[wv][ll][lh * 8];
        const bf16x8 v0 = *(const bf16x8*)&VTs[cur][ll][sb + lh * 8];
        const bf16x8 v1 = *(const bf16x8*)&VTs[cur][16 + ll][sb + lh * 8];
        o0 = __builtin_amdgcn_mfma_f32_16x16x32_bf16(pa, v0, o0, 0, 0, 0);
        o1 = __builtin_amdgcn_mfma_f32_16x16x32_bf16(pa, v1, o1, 0, 0, 0);
        __builtin_amdgcn_s_setprio(0);
      }
    }
    if (more) {
      *(bf16x8*)&Ks[cur ^ 1][sk_slot][sk_d] = nkv;
      *(bf16x8*)&VTs[cur ^ 1][sv_d][sv_s] = nvv;
    }
    cur ^= 1;
  }

#pragma unroll
  for (int r = 0; r < 4; ++r) {
    float s = lsum[r];
    s += __shfl_xor(s, 1); s += __shfl_xor(s, 2);
    s += __shfl_xor(s, 4); s += __shfl_xor(s, 8);
    const float inv = 1.0f / s;
    const size_t row = ((size_t)b * NN + qh * WI + qw_r[r]) * CC + head * HD;
    Ob[row + ll]      = f2bf(o0[r] * inv);
    Ob[row + 16 + ll] = f2bf(o1[r] * inv);
  }
}

// ---------------------------------------------------------------------------
// Final fused GEMM (K=512 via two accumulating passes):
//   out[b][o][n] = relu( O@W32^T + XT@W3^T + b23[o] )
// Replaces outproj_gemm + conv_gemm (no RES round-trip, one launch).
// ---------------------------------------------------------------------------
__global__ __launch_bounds__(256) void final_gemm(
    const u16* __restrict__ Ob, const u16* __restrict__ XT,
    const u16* __restrict__ W32b, const u16* __restrict__ W3b,
    const float* __restrict__ b23, float* __restrict__ out) {
  __shared__ u16 As[64][40];
  __shared__ u16 Ws[64][40];
  const int tid = threadIdx.x;
  const int m0 = blockIdx.x * 64, j0 = blockIdx.y * 64;
  f32x4 acc[2][2] = {};
  gemm_core64(Ob, W32b, m0, j0, As, Ws, acc, tid);   // k = attention-out dims
  gemm_core64(XT, W3b,  m0, j0, As, Ws, acc, tid);   // k = x channels

  const int lane = tid & 63, ll = lane & 15, lh = lane >> 4;
  const int wv = tid >> 6;
  const int wm = (wv >> 1) << 5, wj = (wv & 1) << 5;
  const int b = m0 / NN, n0 = m0 % NN;
#pragma unroll
  for (int js = 0; js < 2; ++js) {
    const int j = j0 + wj + js * 16 + ll;
    const float bj = b23[j];
#pragma unroll
    for (int ms = 0; ms < 2; ++ms) {
      const int nb = n0 + wm + ms * 16 + (lh << 2);
      float4 v;
      v.x = fmaxf(acc[ms][js][0] + bj, 0.0f);
      v.y = fmaxf(acc[ms][js][1] + bj, 0.0f);
      v.z = fmaxf(acc[ms][js][2] + bj, 0.0f);
      v.w = fmaxf(acc[ms][js][3] + bj, 0.0f);
      *(float4*)&out[((size_t)b * CC + j) * NN + nb] = v;
    }
  }
}

extern "C" void kernel_launch(void* const* d_in, const int* in_sizes, int n_in,
                              void* d_out, int out_size, void* d_ws, size_t ws_size,
                              hipStream_t stream) {
  const float* x         = (const float*)d_in[0];
  const float* in_proj_w = (const float*)d_in[1];
  const float* in_proj_b = (const float*)d_in[2];
  const float* out_w     = (const float*)d_in[3];
  const float* out_b     = (const float*)d_in[4];
  const float* conv_w    = (const float*)d_in[5];
  const float* conv_b    = (const float*)d_in[6];
  float* out = (float*)d_out;

  u16* wsb = (u16*)d_ws;
  u16* XT   = wsb;                         // [9216][256] bf16
  u16* Qb   = wsb + (size_t)BUF;           // [B,H,N,32]
  u16* Kb   = wsb + (size_t)2 * BUF;       // [B,H,N,32]
  u16* VTb  = wsb + (size_t)3 * BUF;       // [B,H,32,N]
  u16* Ob   = wsb + (size_t)4 * BUF;       // [9216][256]
  u16* W1b  = wsb + (size_t)5 * BUF;       // [768][256]
  u16* W3b  = W1b + 196608;                // [256][256]
  u16* W32b = W3b + 65536;                 // [256][256]
  float* b23 = (float*)(W32b + 65536);     // [256] fp32

  prep_kernel<<<dim3(2577), dim3(256), 0, stream>>>(
      x, in_proj_w, out_w, conv_w, out_b, conv_b, XT, W1b, W3b, W32b, b23);
  qkv_gemm<<<dim3(72, 6), dim3(256), 0, stream>>>(XT, W1b, in_proj_b, Qb, Kb, VTb);
  attn_mfma<<<dim3(1152), dim3(256), 0, stream>>>(Qb, Kb, VTb, Ob);
  final_gemm<<<dim3(144, 4), dim3(256), 0, stream>>>(Ob, XT, W32b, W3b, b23, out);
}

// Round 20
// 58.164 us; speedup vs baseline: 1.0473x; 1.0473x over previous
//
#include <hip/hip_runtime.h>
#include <math.h>

#define BB 4
#define CC 256
#define HH 48
#define WI 48
#define NN (HH*WI)      // 2304
#define NHEAD 8
#define HD 32
#define PLANE ((size_t)NN*HD)
#define BUF   (BB*NHEAD*NN*HD)      // 2359296 elems per [9216,256] buffer

typedef unsigned short u16;
typedef __attribute__((ext_vector_type(8))) short bf16x8;
typedef __attribute__((ext_vector_type(4))) float f32x4;

__device__ inline u16 f2bf(float f) {          // RNE float->bf16
  union { float f; unsigned u; } v; v.f = f;
  unsigned r = v.u + 0x7FFFu + ((v.u >> 16) & 1u);
  return (u16)(r >> 16);
}
__device__ inline u16 f2bf_rna(float f) {      // cheap round (f>=0)
  union { float f; unsigned u; } v; v.f = f;
  return (u16)((v.u + 0x8000u) >> 16);
}

// ---------------------------------------------------------------------------
// Fused prep: blocks [0,2304): XT[b*N+n][c] = bf16(x[b][c][n]) transpose tiles
//             blocks [2304,2624): fp32->bf16 weight convert (W1|W2|W3)
// ---------------------------------------------------------------------------
__global__ __launch_bounds__(256) void prep_kernel(
    const float* __restrict__ x, const float* __restrict__ w1,
    const float* __restrict__ w2, const float* __restrict__ w3,
    u16* __restrict__ XT, u16* __restrict__ W1b,
    u16* __restrict__ W2b, u16* __restrict__ W3b) {
  __shared__ float T[32][36];
  const int bx = blockIdx.x;
  const int t = threadIdx.x;
  if (bx < 2304) {
    const int n0 = (bx % 72) * 32, c0 = ((bx / 72) & 7) * 32, b = bx / 576;
    const int c = t >> 3, n4 = (t & 7) * 4;
    *(float4*)&T[c][n4] = *(const float4*)&x[((size_t)b * CC + c0 + c) * NN + n0 + n4];
    __syncthreads();
    const int nn = t >> 3, c4 = (t & 7) * 4;
    ushort4 o;
    o.x = f2bf(T[c4 + 0][nn]); o.y = f2bf(T[c4 + 1][nn]);
    o.z = f2bf(T[c4 + 2][nn]); o.w = f2bf(T[c4 + 3][nn]);
    *(ushort4*)&XT[((size_t)b * NN + n0 + nn) * CC + c0 + c4] = o;
  } else {
    const int i = ((bx - 2304) * 256 + t) * 4;
    const float* src; u16* dst; int off;
    if (i < 196608)      { src = w1; dst = W1b; off = i; }
    else if (i < 262144) { src = w2; dst = W2b; off = i - 196608; }
    else                 { src = w3; dst = W3b; off = i - 262144; }
    float4 v = *(const float4*)&src[off];
    ushort4 o = {f2bf(v.x), f2bf(v.y), f2bf(v.z), f2bf(v.w)};
    *(ushort4*)&dst[off] = o;
  }
}

// ---------------------------------------------------------------------------
// MFMA GEMM core 128x128 (R4/R8-proven, used by qkv): K=256, 4 waves 2x2.
// Frag layout (HW-verified): A row=ll, B col=ll, k=lh*8+j; C/D row=lh*4+r, col=ll.
// ---------------------------------------------------------------------------
__device__ __forceinline__ void gemm_core(
    const u16* __restrict__ act, const u16* __restrict__ wb,
    int m0, int j0, u16 (&As)[128][40], u16 (&Ws)[128][40],
    f32x4 (&acc)[4][4], int tid) {
  const int lane = tid & 63, ll = lane & 15, lh = lane >> 4;
  const int wv = tid >> 6;
  const int wm = (wv >> 1) << 6, wj = (wv & 1) << 6;
  const int r_ = tid >> 1;
  const int kh = (tid & 1) << 4;
  for (int k0 = 0; k0 < CC; k0 += 32) {
    __syncthreads();
    bf16x8 a0 = *(const bf16x8*)&act[(size_t)(m0 + r_) * CC + k0 + kh];
    bf16x8 a1 = *(const bf16x8*)&act[(size_t)(m0 + r_) * CC + k0 + kh + 8];
    bf16x8 w0 = *(const bf16x8*)&wb[(size_t)(j0 + r_) * CC + k0 + kh];
    bf16x8 w1 = *(const bf16x8*)&wb[(size_t)(j0 + r_) * CC + k0 + kh + 8];
    *(bf16x8*)&As[r_][kh]     = a0;
    *(bf16x8*)&As[r_][kh + 8] = a1;
    *(bf16x8*)&Ws[r_][kh]     = w0;
    *(bf16x8*)&Ws[r_][kh + 8] = w1;
    __syncthreads();
    bf16x8 af[4], bfv[4];
#pragma unroll
    for (int s = 0; s < 4; ++s) {
      af[s]  = *(const bf16x8*)&As[wm + s * 16 + ll][lh * 8];
      bfv[s] = *(const bf16x8*)&Ws[wj + s * 16 + ll][lh * 8];
    }
#pragma unroll
    for (int ms = 0; ms < 4; ++ms)
#pragma unroll
      for (int js = 0; js < 4; ++js)
        acc[ms][js] = __builtin_amdgcn_mfma_f32_16x16x32_bf16(af[ms], bfv[js], acc[ms][js], 0, 0, 0);
  }
}

// ---------------------------------------------------------------------------
// MFMA GEMM core 64x64 (outproj/conv). 4 waves 2x2, wave = 32x32. LDS 10 KB.
// ---------------------------------------------------------------------------
__device__ __forceinline__ void gemm_core64(
    const u16* __restrict__ act, const u16* __restrict__ wb,
    int m0, int j0, u16 (&As)[64][40], u16 (&Ws)[64][40],
    f32x4 (&acc)[2][2], int tid) {
  const int lane = tid & 63, ll = lane & 15, lh = lane >> 4;
  const int wv = tid >> 6;
  const int wm = (wv >> 1) << 5, wj = (wv & 1) << 5;
  const bool isW = (tid >= 128);
  const int r_ = (tid & 127) >> 1;
  const int kh = (tid & 1) << 4;
  const u16* src = isW ? &wb[(size_t)(j0 + r_) * CC + kh]
                       : &act[(size_t)(m0 + r_) * CC + kh];
  u16* dst = isW ? &Ws[r_][kh] : &As[r_][kh];
  for (int k0 = 0; k0 < CC; k0 += 32) {
    __syncthreads();
    bf16x8 v0 = *(const bf16x8*)(src + k0);
    bf16x8 v1 = *(const bf16x8*)(src + k0 + 8);
    *(bf16x8*)dst       = v0;
    *(bf16x8*)(dst + 8) = v1;
    __syncthreads();
    bf16x8 af[2], bfv[2];
#pragma unroll
    for (int s = 0; s < 2; ++s) {
      af[s]  = *(const bf16x8*)&As[wm + s * 16 + ll][lh * 8];
      bfv[s] = *(const bf16x8*)&Ws[wj + s * 16 + ll][lh * 8];
    }
#pragma unroll
    for (int ms = 0; ms < 2; ++ms)
#pragma unroll
      for (int js = 0; js < 2; ++js)
        acc[ms][js] = __builtin_amdgcn_mfma_f32_16x16x32_bf16(af[ms], bfv[js], acc[ms][js], 0, 0, 0);
  }
}

// ---------------------------------------------------------------------------
// GEMM 1 (128x128): qkv = XT @ W1^T + b1 -> Q, K [B,H,N,32], VT [B,H,32,N]
// ---------------------------------------------------------------------------
__global__ __launch_bounds__(256) void qkv_gemm(
    const u16* __restrict__ XT, const u16* __restrict__ W1b,
    const float* __restrict__ bias,
    u16* __restrict__ Qb, u16* __restrict__ Kb, u16* __restrict__ VTb) {
  __shared__ u16 As[128][40];
  __shared__ u16 Ws[128][40];
  const int tid = threadIdx.x;
  const int m0 = blockIdx.x * 128, j0 = blockIdx.y * 128;
  f32x4 acc[4][4] = {};
  gemm_core(XT, W1b, m0, j0, As, Ws, acc, tid);

  const int lane = tid & 63, ll = lane & 15, lh = lane >> 4;
  const int wv = tid >> 6;
  const int wm = (wv >> 1) << 6, wj = (wv & 1) << 6;
  const int part = blockIdx.y >> 1;            // 0=Q 1=K 2=V (uniform)
  const int b = m0 / NN, n0 = m0 % NN;
#pragma unroll
  for (int js = 0; js < 4; ++js) {
    const int j = j0 + wj + js * 16 + ll;
    const float bj = bias[j];
    const int head = (j >> 5) & 7, d = j & 31;
#pragma unroll
    for (int ms = 0; ms < 4; ++ms) {
      const int nb = n0 + wm + ms * 16 + (lh << 2);
      if (part == 2) {
        ushort4 v = {f2bf(acc[ms][js][0] + bj), f2bf(acc[ms][js][1] + bj),
                     f2bf(acc[ms][js][2] + bj), f2bf(acc[ms][js][3] + bj)};
        *(ushort4*)&VTb[(((size_t)b * NHEAD + head) * HD + d) * NN + nb] = v;
      } else {
        u16* dst = (part == 0 ? Qb : Kb) + ((size_t)b * NHEAD + head) * PLANE;
#pragma unroll
        for (int r = 0; r < 4; ++r)
          dst[(size_t)(nb + r) * HD + d] = f2bf(acc[ms][js][r] + bj);
      }
    }
  }
}

// ---------------------------------------------------------------------------
// MFMA windowed attention (R18-proven BEST): 16x4 query tile, 2-row chunked
// double-buffered clamped staging, setprio, XCD swizzle. LDS 22.3 KB.
// ---------------------------------------------------------------------------
__global__ __launch_bounds__(256) void attn_mfma(
    const u16* __restrict__ Qb, const u16* __restrict__ Kb,
    const u16* __restrict__ VTb, u16* __restrict__ Ob) {
  __shared__ u16 Ks[2][64][32];   // [buf][slot = rr*32+key][dim]
  __shared__ u16 VTs[2][32][72];  // [buf][dim][slot] (pad 72)
  __shared__ u16 Ps[4][16][40];   // per-wave P [query][keyslot]
  const int bid0 = blockIdx.x;
  const int bid  = (bid0 & 7) * 144 + (bid0 >> 3);   // XCD swizzle (bijective)
  const int tile = bid % 36;      // 12 (th) x 3 (tw)
  const int head = (bid / 36) & 7;
  const int b    = bid / 288;
  const int th0 = (tile / 3) * 4, tw0 = (tile % 3) * 16;
  const int tid = threadIdx.x;
  const int wv = tid >> 6, lane = tid & 63;
  const int lh = lane >> 4, ll = lane & 15;
  const size_t plane = ((size_t)b * NHEAD + head) * PLANE;

  const int wlo = max(0, tw0 - 8);
  const int nw  = min(WI, tw0 + 24) - wlo;       // 24 or 32, block-uniform
  const int rlo = max(0, th0 - 8), rhi = min(HH, th0 + 12);   // even count

  const int qh = th0 + wv;                       // wave's query row
  const bf16x8 qfrag = *(const bf16x8*)&Qb[plane + (size_t)(qh * WI + tw0 + ll) * HD + lh * 8];

  int qw_r[4];
  float cb0[4], cb1[4];
  const int wk0 = wlo + ll;
  const int wk1 = wlo + 16 + ll;
#pragma unroll
  for (int r = 0; r < 4; ++r) {
    qw_r[r] = tw0 + (lh << 2) + r;
    cb0[r] = (abs(wk0 - qw_r[r]) <= 8) ? 0.0f : -30000.0f;
    cb1[r] = (wk1 < WI && abs(wk1 - qw_r[r]) <= 8) ? 0.0f : -30000.0f;
  }

  f32x4 o0 = {0.f, 0.f, 0.f, 0.f}, o1 = {0.f, 0.f, 0.f, 0.f};
  const f32x4 zf = {0.f, 0.f, 0.f, 0.f};
  float lsum[4] = {0.f, 0.f, 0.f, 0.f};
  // clamped staging columns: slots >= nw stage col nw-1 data; those slots
  // always have P=0 via cb masks, so values are irrelevant (finite).
  const int sk_slot = tid >> 2, sk_d = (tid & 3) * 8;
  const int sk_rr = sk_slot >> 5;
  const int sk_c  = min(sk_slot & 31, nw - 1);
  const int sv_d = tid >> 3, sv_s = (tid & 7) * 8;
  const int sv_rr = sv_s >> 5;
  const int sv_c  = min(sv_s & 31, nw - 1);
  const float C2 = 0.25501651847296056f;         // (1/sqrt(32)) * log2(e)
  const int nch = (rhi - rlo) >> 1;

  {
    bf16x8 kv = *(const bf16x8*)&Kb[plane + (size_t)((rlo + sk_rr) * WI + wlo + sk_c) * HD + sk_d];
    bf16x8 vv = *(const bf16x8*)&VTb[plane + (size_t)sv_d * NN + (rlo + sv_rr) * WI + wlo + sv_c];
    *(bf16x8*)&Ks[0][sk_slot][sk_d] = kv;
    *(bf16x8*)&VTs[0][sv_d][sv_s] = vv;
  }

  int cur = 0;
  for (int c = 0; c < nch; ++c) {
    const int hk2 = rlo + (c << 1);
    bf16x8 nkv, nvv;
    const bool more = (c + 1 < nch);
    if (more) {
      nkv = *(const bf16x8*)&Kb[plane + (size_t)((hk2 + 2 + sk_rr) * WI + wlo + sk_c) * HD + sk_d];
      nvv = *(const bf16x8*)&VTb[plane + (size_t)sv_d * NN + (hk2 + 2 + sv_rr) * WI + wlo + sv_c];
    }
    __syncthreads();   // buf[cur] complete
#pragma unroll
    for (int rr = 0; rr < 2; ++rr) {
      const int hk = hk2 + rr;
      if (hk >= qh - 8 && hk <= qh + 8) {          // wave-uniform row window
        const int sb = rr << 5;
        __builtin_amdgcn_s_setprio(1);
        const bf16x8 k0 = *(const bf16x8*)&Ks[cur][sb + ll][lh * 8];
        const bf16x8 k1 = *(const bf16x8*)&Ks[cur][sb + 16 + ll][lh * 8];
        f32x4 s0 = __builtin_amdgcn_mfma_f32_16x16x32_bf16(qfrag, k0, zf, 0, 0, 0);
        f32x4 s1 = __builtin_amdgcn_mfma_f32_16x16x32_bf16(qfrag, k1, zf, 0, 0, 0);
#pragma unroll
        for (int r = 0; r < 4; ++r) {
          float e0 = exp2f(fmaf(s0[r], C2, cb0[r]));
          float e1 = exp2f(fmaf(s1[r], C2, cb1[r]));
          lsum[r] += e0 + e1;
          Ps[wv][(lh << 2) + r][ll]      = f2bf_rna(e0);
          Ps[wv][(lh << 2) + r][16 + ll] = f2bf_rna(e1);
        }
        const bf16x8 pa = *(const bf16x8*)&Ps[wv][ll][lh * 8];
        const bf16x8 v0 = *(const bf16x8*)&VTs[cur][ll][sb + lh * 8];
        const bf16x8 v1 = *(const bf16x8*)&VTs[cur][16 + ll][sb + lh * 8];
        o0 = __builtin_amdgcn_mfma_f32_16x16x32_bf16(pa, v0, o0, 0, 0, 0);
        o1 = __builtin_amdgcn_mfma_f32_16x16x32_bf16(pa, v1, o1, 0, 0, 0);
        __builtin_amdgcn_s_setprio(0);
      }
    }
    if (more) {
      *(bf16x8*)&Ks[cur ^ 1][sk_slot][sk_d] = nkv;
      *(bf16x8*)&VTs[cur ^ 1][sv_d][sv_s] = nvv;
    }
    cur ^= 1;
  }

#pragma unroll
  for (int r = 0; r < 4; ++r) {
    float s = lsum[r];
    s += __shfl_xor(s, 1); s += __shfl_xor(s, 2);
    s += __shfl_xor(s, 4); s += __shfl_xor(s, 8);
    const float inv = 1.0f / s;
    const size_t row = ((size_t)b * NN + qh * WI + qw_r[r]) * CC + head * HD;
    Ob[row + ll]      = f2bf(o0[r] * inv);
    Ob[row + 16 + ll] = f2bf(o1[r] * inv);
  }
}

// ---------------------------------------------------------------------------
// GEMM 2 (64x64 tiles): RES[m][c] = bf16( O @ W2^T + b2 + x[b][c][n] )
// ---------------------------------------------------------------------------
__global__ __launch_bounds__(256) void outproj_gemm(
    const u16* __restrict__ Ob, const u16* __restrict__ W2b,
    const float* __restrict__ bias, const float* __restrict__ x,
    u16* __restrict__ RESb) {
  __shared__ u16 As[64][40];
  __shared__ u16 Ws[64][40];
  const int tid = threadIdx.x;
  const int m0 = blockIdx.x * 64, j0 = blockIdx.y * 64;
  f32x4 acc[2][2] = {};
  gemm_core64(Ob, W2b, m0, j0, As, Ws, acc, tid);

  const int lane = tid & 63, ll = lane & 15, lh = lane >> 4;
  const int wv = tid >> 6;
  const int wm = (wv >> 1) << 5, wj = (wv & 1) << 5;
  const int b = m0 / NN, n0 = m0 % NN;
#pragma unroll
  for (int js = 0; js < 2; ++js) {
    const int j = j0 + wj + js * 16 + ll;
    const float bj = bias[j];
#pragma unroll
    for (int ms = 0; ms < 2; ++ms) {
      const int nb = n0 + wm + ms * 16 + (lh << 2);
      float4 xr = *(const float4*)&x[((size_t)b * CC + j) * NN + nb];
      float rr[4] = {acc[ms][js][0] + bj + xr.x, acc[ms][js][1] + bj + xr.y,
                     acc[ms][js][2] + bj + xr.z, acc[ms][js][3] + bj + xr.w};
#pragma unroll
      for (int r = 0; r < 4; ++r)
        RESb[(size_t)(m0 + wm + ms * 16 + (lh << 2) + r) * CC + j] = f2bf(rr[r]);
    }
  }
}

// ---------------------------------------------------------------------------
// GEMM 3 (64x64 tiles): out[b][c][n] = relu( RES @ W3^T + b3 )  (fp32 output)
// ---------------------------------------------------------------------------
__global__ __launch_bounds__(256) void conv_gemm(
    const u16* __restrict__ RESb, const u16* __restrict__ W3b,
    const float* __restrict__ bias, float* __restrict__ out) {
  __shared__ u16 As[64][40];
  __shared__ u16 Ws[64][40];
  const int tid = threadIdx.x;
  const int m0 = blockIdx.x * 64, j0 = blockIdx.y * 64;
  f32x4 acc[2][2] = {};
  gemm_core64(RESb, W3b, m0, j0, As, Ws, acc, tid);

  const int lane = tid & 63, ll = lane & 15, lh = lane >> 4;
  const int wv = tid >> 6;
  const int wm = (wv >> 1) << 5, wj = (wv & 1) << 5;
  const int b = m0 / NN, n0 = m0 % NN;
#pragma unroll
  for (int js = 0; js < 2; ++js) {
    const int j = j0 + wj + js * 16 + ll;
    const float bj = bias[j];
#pragma unroll
    for (int ms = 0; ms < 2; ++ms) {
      const int nb = n0 + wm + ms * 16 + (lh << 2);
      float4 v;
      v.x = fmaxf(acc[ms][js][0] + bj, 0.0f);
      v.y = fmaxf(acc[ms][js][1] + bj, 0.0f);
      v.z = fmaxf(acc[ms][js][2] + bj, 0.0f);
      v.w = fmaxf(acc[ms][js][3] + bj, 0.0f);
      *(float4*)&out[((size_t)b * CC + j) * NN + nb] = v;
    }
  }
}

extern "C" void kernel_launch(void* const* d_in, const int* in_sizes, int n_in,
                              void* d_out, int out_size, void* d_ws, size_t ws_size,
                              hipStream_t stream) {
  const float* x         = (const float*)d_in[0];
  const float* in_proj_w = (const float*)d_in[1];
  const float* in_proj_b = (const float*)d_in[2];
  const float* out_w     = (const float*)d_in[3];
  const float* out_b     = (const float*)d_in[4];
  const float* conv_w    = (const float*)d_in[5];
  const float* conv_b    = (const float*)d_in[6];
  float* out = (float*)d_out;

  u16* wsb = (u16*)d_ws;
  u16* XT   = wsb;                         // [9216][256] bf16
  u16* Qb   = wsb + (size_t)BUF;           // [B,H,N,32]
  u16* Kb   = wsb + (size_t)2 * BUF;       // [B,H,N,32]
  u16* VTb  = wsb + (size_t)3 * BUF;       // [B,H,32,N]
  u16* Ob   = wsb + (size_t)4 * BUF;       // [9216][256]
  u16* RESb = wsb + (size_t)5 * BUF;       // [9216][256]
  u16* W1b  = wsb + (size_t)6 * BUF;       // [768][256]
  u16* W2b  = W1b + 196608;                // [256][256]
  u16* W3b  = W2b + 65536;                 // [256][256]

  prep_kernel<<<dim3(2624), dim3(256), 0, stream>>>(x, in_proj_w, out_w, conv_w,
                                                    XT, W1b, W2b, W3b);
  qkv_gemm<<<dim3(72, 6), dim3(256), 0, stream>>>(XT, W1b, in_proj_b, Qb, Kb, VTb);
  attn_mfma<<<dim3(1152), dim3(256), 0, stream>>>(Qb, Kb, VTb, Ob);
  outproj_gemm<<<dim3(144, 4), dim3(256), 0, stream>>>(Ob, W2b, out_b, x, RESb);
  conv_gemm<<<dim3(144, 4), dim3(256), 0, stream>>>(RESb, W3b, conv_b, out);
}